// Round 1
// baseline (853.437 us; speedup 1.0000x reference)
//
#include <hip/hip_runtime.h>

#define NROWS 16384
#define OBSD 512
#define ENCD 512
#define ACTD 64
#define KEXP 8

// ---------------- init: zero accumulators, build B_full = [eye; B_rest] ---
__global__ __launch_bounds__(256) void init_ws_k(
    float* __restrict__ Bfull, const float* __restrict__ Brest,
    float* __restrict__ loss, int* __restrict__ counts, int* __restrict__ cursor) {
  int tid = blockIdx.x * blockDim.x + threadIdx.x;
  int nthr = gridDim.x * blockDim.x;
  if (tid == 0) *loss = 0.f;
  if (tid < KEXP) { counts[tid] = 0; cursor[tid] = 0; }
  const int t0 = ACTD * ENCD;  // expert 0: eye(ENC)[:ACT]  -> B0[a][e] = (a==e)
  for (int i = tid; i < t0; i += nthr) {
    int a = i / ENCD, e = i % ENCD;
    Bfull[i] = (a == e) ? 1.f : 0.f;
  }
  const int tr = (KEXP - 1) * ACTD * ENCD;
  for (int i = tid; i < tr; i += nthr) Bfull[t0 + i] = Brest[i];
}

// ---------------- encoder GEMM: C[m][n] = sum_k X[m][k] * W[n][k] ----------
// 64x64 tile, BK=32, 256 thr, 4x4 microtile. LDS stored K-major so the inner
// loop reads are float4 (ds_read_b128). Second dim padded to 68 for 16B align.
__global__ __launch_bounds__(256) void enc_gemm_k(
    const float* __restrict__ X, const float* __restrict__ W,
    float* __restrict__ C, int M, int Nc, int Kd) {
  __shared__ float Xs[32][68];
  __shared__ float Ws[32][68];
  const int tid = threadIdx.x;
  const int tx = tid & 15, ty = tid >> 4;
  const int row0 = blockIdx.y * 64, col0 = blockIdx.x * 64;
  float acc[4][4] = {};
  for (int k0 = 0; k0 < Kd; k0 += 32) {
#pragma unroll
    for (int i = 0; i < 8; i++) {
      int idx = tid + i * 256;
      int c = idx & 31, m = idx >> 5;
      Xs[c][m] = X[(size_t)(row0 + m) * Kd + k0 + c];
      Ws[c][m] = W[(size_t)(col0 + m) * Kd + k0 + c];
    }
    __syncthreads();
#pragma unroll
    for (int kk = 0; kk < 32; kk++) {
      float4 av = *(const float4*)&Xs[kk][ty * 4];
      float4 bv = *(const float4*)&Ws[kk][tx * 4];
      float a[4] = {av.x, av.y, av.z, av.w};
      float b[4] = {bv.x, bv.y, bv.z, bv.w};
#pragma unroll
      for (int i = 0; i < 4; i++)
#pragma unroll
        for (int j = 0; j < 4; j++) acc[i][j] += a[i] * b[j];
    }
    __syncthreads();
  }
#pragma unroll
  for (int i = 0; i < 4; i++) {
    float4 v = {acc[i][0], acc[i][1], acc[i][2], acc[i][3]};
    *(float4*)&C[(size_t)(row0 + ty * 4 + i) * Nc + col0 + tx * 4] = v;
  }
}

// ---------------- routing: one wave per row, argmax of 8 logits ------------
__global__ __launch_bounds__(256) void routing_k(
    const float* __restrict__ X0e, const float* __restrict__ Cw,
    const float* __restrict__ Cb, int* __restrict__ inds,
    int* __restrict__ counts) {
  __shared__ float sCw[KEXP][ENCD];  // 16 KB
  const int tid = threadIdx.x;
  for (int i = tid; i < KEXP * ENCD; i += 256) sCw[i / ENCD][i % ENCD] = Cw[i];
  __syncthreads();
  const int wave = tid >> 6, lane = tid & 63;
  const int n = blockIdx.x * 4 + wave;
  float acc[KEXP] = {};
  const float* xr = X0e + (size_t)n * ENCD;
  for (int h = lane; h < ENCD; h += 64) {
    float x = xr[h];
#pragma unroll
    for (int e = 0; e < KEXP; e++) acc[e] += x * sCw[e][h];
  }
#pragma unroll
  for (int e = 0; e < KEXP; e++) {
#pragma unroll
    for (int off = 32; off > 0; off >>= 1) acc[e] += __shfl_xor(acc[e], off, 64);
  }
  if (lane == 0) {
    int best = 0;
    float bv = acc[0] + Cb[0];
#pragma unroll
    for (int e = 1; e < KEXP; e++) {
      float v = acc[e] + Cb[e];
      if (v > bv) { bv = v; best = e; }  // strict > : first max wins (jnp.argmax)
    }
    inds[n] = best;
    atomicAdd(&counts[best], 1);
  }
}

// ---------------- prefix (K=8, one thread) --------------------------------
__global__ void prefix_k(const int* __restrict__ counts, int* __restrict__ cursor,
                         int* __restrict__ starts) {
  if (threadIdx.x == 0 && blockIdx.x == 0) {
    int s = 0;
    for (int k = 0; k < KEXP; k++) {
      starts[k] = s;
      cursor[k] = s;
      s += counts[k];
    }
    starts[KEXP] = s;
  }
}

// ---------------- scatter rows into per-expert lists ----------------------
__global__ __launch_bounds__(256) void scatter_k(
    const int* __restrict__ inds, int* __restrict__ cursor,
    int* __restrict__ rowlist) {
  int n = blockIdx.x * blockDim.x + threadIdx.x;
  if (n < NROWS) {
    int r = inds[n];
    int pos = atomicAdd(&cursor[r], 1);
    rowlist[pos] = n;
  }
}

// ---------------- grouped GEMM + fused (X1e - pred)^2 reduction -----------
// grid: x = col tile (8), y = row tile (up to 256), z = expert (8)
__global__ __launch_bounds__(256) void grouped_sq_k(
    const float* __restrict__ X0e, const float* __restrict__ X1e,
    const float* __restrict__ U, const float* __restrict__ Aall,
    const float* __restrict__ Bfull, const int* __restrict__ rowlist,
    const int* __restrict__ starts, float* __restrict__ loss) {
  const int k = blockIdx.z;
  const int start = starts[k];
  const int cnt = starts[k + 1] - start;
  const int t = blockIdx.y;
  if (t * 64 >= cnt) return;  // uniform early exit, before any barrier
  __shared__ float Ls[32][68];
  __shared__ float Rs[32][68];
  __shared__ int ridx[64];
  __shared__ float red[256];
  const int tid = threadIdx.x;
  if (tid < 64) {
    int p = t * 64 + tid;
    ridx[tid] = (p < cnt) ? rowlist[start + p] : -1;
  }
  __syncthreads();
  const int tx = tid & 15, ty = tid >> 4;
  const int col0 = blockIdx.x * 64;
  const float* Ak = Aall + (size_t)k * ENCD * ENCD;
  float acc[4][4] = {};
  // pred[m][e] += sum_h X0e[m][h] * A[k][e][h]
  for (int k0 = 0; k0 < ENCD; k0 += 32) {
#pragma unroll
    for (int i = 0; i < 8; i++) {
      int idx = tid + i * 256;
      int c = idx & 31, m = idx >> 5;
      int rn = ridx[m];
      Ls[c][m] = (rn >= 0) ? X0e[(size_t)rn * ENCD + k0 + c] : 0.f;
      Rs[c][m] = Ak[(size_t)(col0 + m) * ENCD + k0 + c];
    }
    __syncthreads();
#pragma unroll
    for (int kk = 0; kk < 32; kk++) {
      float4 av = *(const float4*)&Ls[kk][ty * 4];
      float4 bv = *(const float4*)&Rs[kk][tx * 4];
      float a[4] = {av.x, av.y, av.z, av.w};
      float b[4] = {bv.x, bv.y, bv.z, bv.w};
#pragma unroll
      for (int i = 0; i < 4; i++)
#pragma unroll
        for (int j = 0; j < 4; j++) acc[i][j] += a[i] * b[j];
    }
    __syncthreads();
  }
  // pred[m][e] += sum_a U[m][a] * Bfull[k][a][e]
  const float* Bk = Bfull + (size_t)k * ACTD * ENCD;
  for (int a0 = 0; a0 < ACTD; a0 += 32) {
#pragma unroll
    for (int i = 0; i < 8; i++) {
      int idx = tid + i * 256;
      {
        int c = idx & 31, m = idx >> 5;
        int rn = ridx[m];
        Ls[c][m] = (rn >= 0) ? U[(size_t)rn * ACTD + a0 + c] : 0.f;
      }
      {
        int e = idx & 63, aa = idx >> 6;
        Rs[aa][e] = Bk[(size_t)(a0 + aa) * ENCD + col0 + e];
      }
    }
    __syncthreads();
#pragma unroll
    for (int kk = 0; kk < 32; kk++) {
      float4 av = *(const float4*)&Ls[kk][ty * 4];
      float4 bv = *(const float4*)&Rs[kk][tx * 4];
      float a[4] = {av.x, av.y, av.z, av.w};
      float b[4] = {bv.x, bv.y, bv.z, bv.w};
#pragma unroll
      for (int i = 0; i < 4; i++)
#pragma unroll
        for (int j = 0; j < 4; j++) acc[i][j] += a[i] * b[j];
    }
    __syncthreads();
  }
  // fused epilogue: sum (X1e - pred)^2 over this tile
  float sq = 0.f;
#pragma unroll
  for (int i = 0; i < 4; i++) {
    int rn = ridx[ty * 4 + i];
    if (rn >= 0) {
      float4 x1 = *(const float4*)&X1e[(size_t)rn * ENCD + col0 + tx * 4];
      float x1a[4] = {x1.x, x1.y, x1.z, x1.w};
#pragma unroll
      for (int j = 0; j < 4; j++) {
        float d = x1a[j] - acc[i][j];
        sq += d * d;
      }
    }
  }
  red[tid] = sq;
  __syncthreads();
  for (int s = 128; s > 0; s >>= 1) {
    if (tid < s) red[tid] += red[tid + s];
    __syncthreads();
  }
  if (tid == 0) atomicAdd(loss, red[0]);
}

// ---------------- finalize ------------------------------------------------
__global__ void finalize_k(const float* __restrict__ loss, float* __restrict__ out) {
  if (threadIdx.x == 0 && blockIdx.x == 0)
    out[0] = loss[0] * (1.0f / ((float)ENCD * (float)NROWS));  // ALPHA = 1
}

extern "C" void kernel_launch(void* const* d_in, const int* in_sizes, int n_in,
                              void* d_out, int out_size, void* d_ws, size_t ws_size,
                              hipStream_t stream) {
  const float* X1 = (const float*)d_in[0];
  const float* X0 = (const float*)d_in[1];
  const float* U = (const float*)d_in[2];
  const float* W = (const float*)d_in[3];
  const float* Aall = (const float*)d_in[4];
  const float* Brest = (const float*)d_in[5];
  const float* Cw = (const float*)d_in[6];
  const float* Cb = (const float*)d_in[7];
  float* out = (float*)d_out;

  float* ws = (float*)d_ws;
  float* X1e = ws;                                   // N*ENC
  float* X0e = X1e + (size_t)NROWS * ENCD;           // N*ENC
  float* Bfull = X0e + (size_t)NROWS * ENCD;         // K*ACT*ENC
  float* loss = Bfull + (size_t)KEXP * ACTD * ENCD;  // 1
  int* inds = (int*)(loss + 1);                      // N
  int* rowlist = inds + NROWS;                       // N
  int* counts = rowlist + NROWS;                     // K
  int* cursor = counts + KEXP;                       // K
  int* starts = cursor + KEXP;                       // K+1

  init_ws_k<<<256, 256, 0, stream>>>(Bfull, Brest, loss, counts, cursor);

  dim3 gE(ENCD / 64, NROWS / 64);
  enc_gemm_k<<<gE, 256, 0, stream>>>(X1, W, X1e, NROWS, ENCD, OBSD);
  enc_gemm_k<<<gE, 256, 0, stream>>>(X0, W, X0e, NROWS, ENCD, OBSD);

  routing_k<<<NROWS / 4, 256, 0, stream>>>(X0e, Cw, Cb, inds, counts);
  prefix_k<<<1, 1, 0, stream>>>(counts, cursor, starts);
  scatter_k<<<NROWS / 256, 256, 0, stream>>>(inds, cursor, rowlist);

  dim3 gS(ENCD / 64, NROWS / 64, KEXP);
  grouped_sq_k<<<gS, 256, 0, stream>>>(X0e, X1e, U, Aall, Bfull, rowlist, starts, loss);

  finalize_k<<<1, 64, 0, stream>>>(loss, out);
}

// Round 2
// 375.322 us; speedup vs baseline: 2.2739x; 2.2739x over previous
//
#include <hip/hip_runtime.h>

#define NROWS 16384
#define OBSD 512
#define ENCD 512
#define ACTD 64
#define KEXP 8

typedef __attribute__((ext_vector_type(8))) short bf16x8;
typedef __attribute__((ext_vector_type(4))) float f32x4;
typedef __attribute__((ext_vector_type(8))) unsigned short ushort8;
typedef __attribute__((address_space(3))) unsigned char lds_byte;
typedef __attribute__((address_space(1))) unsigned char glb_byte;

__device__ __forceinline__ unsigned short f2bf(float f) {
  unsigned int u = __float_as_uint(f);
  u = (u + 0x7FFFu + ((u >> 16) & 1u)) >> 16;
  return (unsigned short)u;
}
__device__ __forceinline__ float bf2f(unsigned short h) {
  return __uint_as_float(((unsigned int)h) << 16);
}
__device__ __forceinline__ void gload_lds16(const unsigned short* g, unsigned short* l) {
  __builtin_amdgcn_global_load_lds((const glb_byte*)g, (lds_byte*)l, 16, 0, 0);
}

// ---------------- init: zero accums, build BfullT (bf16) = [eye; B_rest]^T --
__global__ __launch_bounds__(256) void init_ws_k(
    unsigned short* __restrict__ BfT, const float* __restrict__ Brest,
    float* __restrict__ loss, int* __restrict__ counts, int* __restrict__ cursor) {
  int tid = blockIdx.x * blockDim.x + threadIdx.x;
  int nthr = gridDim.x * blockDim.x;
  if (tid == 0) *loss = 0.f;
  if (tid < KEXP) { counts[tid] = 0; cursor[tid] = 0; }
  const int per = ENCD * ACTD;  // BfT[k][e][a]
  for (int i = tid; i < KEXP * per; i += nthr) {
    int k = i / per, rem = i - k * per;
    int e = rem >> 6, a = rem & 63;
    float v;
    if (k == 0) v = (e == a) ? 1.f : 0.f;
    else v = Brest[((size_t)(k - 1) * ACTD + a) * ENCD + e];
    BfT[i] = f2bf(v);
  }
}

// ---------------- fp32 -> bf16 convert, 8 elems/thread ---------------------
__global__ __launch_bounds__(256) void tobf16_k(const float* __restrict__ src,
                                                unsigned short* __restrict__ dst,
                                                int n8) {
  int i = blockIdx.x * 256 + threadIdx.x;
  if (i >= n8) return;
  const float4* s = (const float4*)src + (size_t)i * 2;
  float4 a = s[0], b = s[1];
  ushort8 r;
  r[0] = f2bf(a.x); r[1] = f2bf(a.y); r[2] = f2bf(a.z); r[3] = f2bf(a.w);
  r[4] = f2bf(b.x); r[5] = f2bf(b.y); r[6] = f2bf(b.z); r[7] = f2bf(b.w);
  *(ushort8*)&dst[(size_t)i * 8] = r;
}

// ---------------- G = C_w @ W_enc  (fp32, exact routing matrix) ------------
__global__ __launch_bounds__(256) void gmat_k(const float* __restrict__ Cw,
                                              const float* __restrict__ W,
                                              float* __restrict__ G) {
  int idx = blockIdx.x * 256 + threadIdx.x;  // 8*512 outputs
  int e = idx >> 9, o = idx & 511;
  float s = 0.f;
  for (int h = 0; h < ENCD; h++) s += Cw[e * ENCD + h] * W[(size_t)h * OBSD + o];
  G[idx] = s;
}

// ---------------- routing: argmax over 8 of  X0 @ G.T + Cb  (fp32 exact) ---
__global__ __launch_bounds__(256) void routing_k(
    const float* __restrict__ X0, const float* __restrict__ G,
    const float* __restrict__ Cb, int* __restrict__ inds,
    int* __restrict__ counts) {
  __shared__ float sG[KEXP][OBSD];  // 16 KB
  const int tid = threadIdx.x;
  for (int i = tid; i < KEXP * OBSD; i += 256) sG[i / OBSD][i % OBSD] = G[i];
  __syncthreads();
  const int wave = tid >> 6, lane = tid & 63;
  const int n = blockIdx.x * 4 + wave;
  float acc[KEXP] = {};
  const float* xr = X0 + (size_t)n * OBSD;
  for (int h = lane; h < OBSD; h += 64) {
    float x = xr[h];
#pragma unroll
    for (int e = 0; e < KEXP; e++) acc[e] += x * sG[e][h];
  }
#pragma unroll
  for (int e = 0; e < KEXP; e++) {
#pragma unroll
    for (int off = 32; off > 0; off >>= 1) acc[e] += __shfl_xor(acc[e], off, 64);
  }
  if (lane == 0) {
    int best = 0;
    float bv = acc[0] + Cb[0];
#pragma unroll
    for (int e = 1; e < KEXP; e++) {
      float v = acc[e] + Cb[e];
      if (v > bv) { bv = v; best = e; }  // strict >: first max wins (jnp.argmax)
    }
    inds[n] = best;
    atomicAdd(&counts[best], 1);
  }
}

__global__ void prefix_k(const int* __restrict__ counts, int* __restrict__ cursor,
                         int* __restrict__ starts) {
  if (threadIdx.x == 0 && blockIdx.x == 0) {
    int s = 0;
    for (int k = 0; k < KEXP; k++) { starts[k] = s; cursor[k] = s; s += counts[k]; }
    starts[KEXP] = s;
  }
}

__global__ __launch_bounds__(256) void scatter_k(
    const int* __restrict__ inds, int* __restrict__ cursor,
    int* __restrict__ rowlist) {
  int n = blockIdx.x * blockDim.x + threadIdx.x;
  if (n < NROWS) {
    int pos = atomicAdd(&cursor[inds[n]], 1);
    rowlist[pos] = n;
  }
}

// ---------------- encoder MFMA GEMM: E = X @ W^T (bf16 in, bf16 out) -------
// 128x128 tile, BK=32, 4 waves (2x2), 16x16x32 bf16 MFMA, global_load_lds
// staging with both-sides 16B-slot XOR swizzle (slot ^= (row>>1)&3).
__global__ __launch_bounds__(256, 2) void enc_mfma_k(
    const unsigned short* __restrict__ X1bf, const unsigned short* __restrict__ X0bf,
    const unsigned short* __restrict__ Wbf, unsigned short* __restrict__ X1ebf,
    unsigned short* __restrict__ X0ebf) {
  __shared__ unsigned short As[128 * 32];
  __shared__ unsigned short Bs[128 * 32];
  const int tid = threadIdx.x;
  // XCD-aware bijective swizzle (nwg = 1024, %8==0); logical id: col fastest
  const int nxy = 512, nwg = 1024, cpx = nwg >> 3;
  int bid = blockIdx.x + 4 * (blockIdx.y + 128 * blockIdx.z);
  int lid = (bid & 7) * cpx + (bid >> 3);
  int lz = lid / nxy;
  int rem = lid - lz * nxy;
  int col0 = (rem & 3) * 128;
  int row0 = (rem >> 2) * 128;
  const unsigned short* X = lz ? X0bf : X1bf;
  unsigned short* E = lz ? X0ebf : X1ebf;

  const int lane = tid & 63, w = tid >> 6;
  const int wr = w >> 1, wc = w & 1;
  const int gslot = ((tid & 3) ^ ((tid >> 3) & 3)) * 8;  // pre-swizzled k-slot
  const int srow = tid >> 2;                             // staging row 0..63
  const int ldsoff = tid * 8;                            // linear LDS dest
  const int rslot = ((lane >> 4) ^ (((lane & 15) >> 1) & 3)) * 8;  // read slot
  const int arow = wr * 64 + (lane & 15);
  const int brow = wc * 64 + (lane & 15);

  f32x4 acc[4][4] = {};
  for (int k0 = 0; k0 < OBSD; k0 += 32) {
    gload_lds16(X + (size_t)(row0 + srow) * OBSD + k0 + gslot, &As[ldsoff]);
    gload_lds16(X + (size_t)(row0 + 64 + srow) * OBSD + k0 + gslot, &As[2048 + ldsoff]);
    gload_lds16(Wbf + (size_t)(col0 + srow) * OBSD + k0 + gslot, &Bs[ldsoff]);
    gload_lds16(Wbf + (size_t)(col0 + 64 + srow) * OBSD + k0 + gslot, &Bs[2048 + ldsoff]);
    __syncthreads();
    bf16x8 af[4], bfr[4];
#pragma unroll
    for (int m = 0; m < 4; m++) af[m] = *(const bf16x8*)&As[(arow + m * 16) * 32 + rslot];
#pragma unroll
    for (int n = 0; n < 4; n++) bfr[n] = *(const bf16x8*)&Bs[(brow + n * 16) * 32 + rslot];
#pragma unroll
    for (int m = 0; m < 4; m++)
#pragma unroll
      for (int n = 0; n < 4; n++)
        acc[m][n] = __builtin_amdgcn_mfma_f32_16x16x32_bf16(af[m], bfr[n], acc[m][n], 0, 0, 0);
    __syncthreads();
  }
#pragma unroll
  for (int m = 0; m < 4; m++) {
    int rg = row0 + wr * 64 + m * 16 + (lane >> 4) * 4;
#pragma unroll
    for (int n = 0; n < 4; n++) {
      int cg = col0 + wc * 64 + n * 16 + (lane & 15);
#pragma unroll
      for (int r = 0; r < 4; r++) E[(size_t)(rg + r) * ENCD + cg] = f2bf(acc[m][n][r]);
    }
  }
}

// ---------------- grouped MFMA GEMM + fused (X1e - pred)^2 -----------------
// pred = X0e[rows] @ A_k^T + U[rows] @ BfT_k^T ; rows gathered via rowlist.
__global__ __launch_bounds__(256, 2) void grouped_mfma_k(
    const unsigned short* __restrict__ X0ebf, const unsigned short* __restrict__ X1ebf,
    const unsigned short* __restrict__ Ubf, const unsigned short* __restrict__ Abf,
    const unsigned short* __restrict__ BfTbf, const int* __restrict__ rowlist,
    const int* __restrict__ starts, float* __restrict__ loss) {
  const int tid = threadIdx.x;
  const int nxy = 512, nwg = 4096, cpx = nwg >> 3;
  int bid = blockIdx.x + 4 * (blockIdx.y + 128 * blockIdx.z);
  int lid = (bid & 7) * cpx + (bid >> 3);
  int k = lid / nxy;
  int rem = lid - k * nxy;
  int col0 = (rem & 3) * 128;
  int tile = rem >> 2;

  const int start = starts[k];
  const int cnt = starts[k + 1] - start;
  if (tile * 128 >= cnt) return;  // uniform early exit before barriers

  __shared__ unsigned short As[128 * 32];
  __shared__ unsigned short Bs[128 * 32];
  __shared__ int ridx[128];
  __shared__ float red[4];

  if (tid < 128) {
    int p = tile * 128 + tid;
    ridx[tid] = rowlist[start + (p < cnt ? p : 0)];
  }
  __syncthreads();

  const int lane = tid & 63, w = tid >> 6;
  const int wr = w >> 1, wc = w & 1;
  const int gslot = ((tid & 3) ^ ((tid >> 3) & 3)) * 8;
  const int srow = tid >> 2;
  const int ldsoff = tid * 8;
  const int rslot = ((lane >> 4) ^ (((lane & 15) >> 1) & 3)) * 8;
  const int arow = wr * 64 + (lane & 15);
  const int brow = wc * 64 + (lane & 15);
  const int rn0 = ridx[srow];
  const int rn1 = ridx[64 + srow];

  f32x4 acc[4][4] = {};
  const unsigned short* Ak = Abf + (size_t)k * ENCD * ENCD;
  for (int k0 = 0; k0 < ENCD; k0 += 32) {
    gload_lds16(X0ebf + (size_t)rn0 * ENCD + k0 + gslot, &As[ldsoff]);
    gload_lds16(X0ebf + (size_t)rn1 * ENCD + k0 + gslot, &As[2048 + ldsoff]);
    gload_lds16(Ak + (size_t)(col0 + srow) * ENCD + k0 + gslot, &Bs[ldsoff]);
    gload_lds16(Ak + (size_t)(col0 + 64 + srow) * ENCD + k0 + gslot, &Bs[2048 + ldsoff]);
    __syncthreads();
    bf16x8 af[4], bfr[4];
#pragma unroll
    for (int m = 0; m < 4; m++) af[m] = *(const bf16x8*)&As[(arow + m * 16) * 32 + rslot];
#pragma unroll
    for (int n = 0; n < 4; n++) bfr[n] = *(const bf16x8*)&Bs[(brow + n * 16) * 32 + rslot];
#pragma unroll
    for (int m = 0; m < 4; m++)
#pragma unroll
      for (int n = 0; n < 4; n++)
        acc[m][n] = __builtin_amdgcn_mfma_f32_16x16x32_bf16(af[m], bfr[n], acc[m][n], 0, 0, 0);
    __syncthreads();
  }
  const unsigned short* BfTk = BfTbf + (size_t)k * ENCD * ACTD;
  for (int a0 = 0; a0 < ACTD; a0 += 32) {
    gload_lds16(Ubf + (size_t)rn0 * ACTD + a0 + gslot, &As[ldsoff]);
    gload_lds16(Ubf + (size_t)rn1 * ACTD + a0 + gslot, &As[2048 + ldsoff]);
    gload_lds16(BfTk + (size_t)(col0 + srow) * ACTD + a0 + gslot, &Bs[ldsoff]);
    gload_lds16(BfTk + (size_t)(col0 + 64 + srow) * ACTD + a0 + gslot, &Bs[2048 + ldsoff]);
    __syncthreads();
    bf16x8 af[4], bfr[4];
#pragma unroll
    for (int m = 0; m < 4; m++) af[m] = *(const bf16x8*)&As[(arow + m * 16) * 32 + rslot];
#pragma unroll
    for (int n = 0; n < 4; n++) bfr[n] = *(const bf16x8*)&Bs[(brow + n * 16) * 32 + rslot];
#pragma unroll
    for (int m = 0; m < 4; m++)
#pragma unroll
      for (int n = 0; n < 4; n++)
        acc[m][n] = __builtin_amdgcn_mfma_f32_16x16x32_bf16(af[m], bfr[n], acc[m][n], 0, 0, 0);
    __syncthreads();
  }
  // fused epilogue: sum (X1e - pred)^2 over valid rows of this tile
  float sq = 0.f;
#pragma unroll
  for (int m = 0; m < 4; m++) {
    int lr0 = wr * 64 + m * 16 + (lane >> 4) * 4;
#pragma unroll
    for (int n = 0; n < 4; n++) {
      int cg = col0 + wc * 64 + n * 16 + (lane & 15);
#pragma unroll
      for (int r = 0; r < 4; r++) {
        int lr = lr0 + r;
        if (tile * 128 + lr < cnt) {
          float x1 = bf2f(X1ebf[(size_t)ridx[lr] * ENCD + cg]);
          float d = x1 - acc[m][n][r];
          sq += d * d;
        }
      }
    }
  }
#pragma unroll
  for (int off = 32; off > 0; off >>= 1) sq += __shfl_xor(sq, off, 64);
  if (lane == 0) red[w] = sq;
  __syncthreads();
  if (tid == 0) atomicAdd(loss, red[0] + red[1] + red[2] + red[3]);
}

__global__ void finalize_k(const float* __restrict__ loss, float* __restrict__ out) {
  if (threadIdx.x == 0 && blockIdx.x == 0)
    out[0] = loss[0] * (1.0f / ((float)ENCD * (float)NROWS));
}

extern "C" void kernel_launch(void* const* d_in, const int* in_sizes, int n_in,
                              void* d_out, int out_size, void* d_ws, size_t ws_size,
                              hipStream_t stream) {
  const float* X1 = (const float*)d_in[0];
  const float* X0 = (const float*)d_in[1];
  const float* U = (const float*)d_in[2];
  const float* W = (const float*)d_in[3];
  const float* Aall = (const float*)d_in[4];
  const float* Brest = (const float*)d_in[5];
  const float* Cw = (const float*)d_in[6];
  const float* Cb = (const float*)d_in[7];
  float* out = (float*)d_out;

  char* p = (char*)d_ws;
  auto alloc = [&](size_t bytes) { char* r = p; p += (bytes + 255) & ~(size_t)255; return r; };
  unsigned short* X1bf = (unsigned short*)alloc((size_t)NROWS * OBSD * 2);
  unsigned short* X0bf = (unsigned short*)alloc((size_t)NROWS * OBSD * 2);
  unsigned short* Ubf = (unsigned short*)alloc((size_t)NROWS * ACTD * 2);
  unsigned short* Wbf = (unsigned short*)alloc((size_t)ENCD * OBSD * 2);
  unsigned short* Abf = (unsigned short*)alloc((size_t)KEXP * ENCD * ENCD * 2);
  unsigned short* BfT = (unsigned short*)alloc((size_t)KEXP * ENCD * ACTD * 2);
  unsigned short* X1ebf = (unsigned short*)alloc((size_t)NROWS * ENCD * 2);
  unsigned short* X0ebf = (unsigned short*)alloc((size_t)NROWS * ENCD * 2);
  float* G = (float*)alloc(KEXP * OBSD * 4);
  float* loss = (float*)alloc(256);
  int* inds = (int*)alloc(NROWS * 4);
  int* rowlist = (int*)alloc(NROWS * 4);
  int* counts = (int*)alloc(64);
  int* cursor = (int*)alloc(64);
  int* starts = (int*)alloc(64);

  init_ws_k<<<256, 256, 0, stream>>>(BfT, Brest, loss, counts, cursor);
  tobf16_k<<<NROWS * OBSD / 8 / 256, 256, 0, stream>>>(X1, X1bf, NROWS * OBSD / 8);
  tobf16_k<<<NROWS * OBSD / 8 / 256, 256, 0, stream>>>(X0, X0bf, NROWS * OBSD / 8);
  tobf16_k<<<NROWS * ACTD / 8 / 256, 256, 0, stream>>>(U, Ubf, NROWS * ACTD / 8);
  tobf16_k<<<ENCD * OBSD / 8 / 256, 256, 0, stream>>>(W, Wbf, ENCD * OBSD / 8);
  tobf16_k<<<KEXP * ENCD * ENCD / 8 / 256, 256, 0, stream>>>(Aall, Abf, KEXP * ENCD * ENCD / 8);

  gmat_k<<<KEXP * OBSD / 256, 256, 0, stream>>>(Cw, W, G);
  routing_k<<<NROWS / 4, 256, 0, stream>>>(X0, G, Cb, inds, counts);
  prefix_k<<<1, 1, 0, stream>>>(counts, cursor, starts);
  scatter_k<<<NROWS / 256, 256, 0, stream>>>(inds, cursor, rowlist);

  enc_mfma_k<<<dim3(4, 128, 2), 256, 0, stream>>>(X1bf, X0bf, Wbf, X1ebf, X0ebf);
  grouped_mfma_k<<<dim3(4, 128, 8), 256, 0, stream>>>(X0ebf, X1ebf, Ubf, Abf, BfT,
                                                      rowlist, starts, loss);
  finalize_k<<<1, 64, 0, stream>>>(loss, out);
}

// Round 3
// 126.436 us; speedup vs baseline: 6.7500x; 2.9685x over previous
//
#include <hip/hip_runtime.h>

#define NROWS 16384
#define OBSD 512
#define ENCD 512
#define ACTD 64
#define KEXP 8

typedef __attribute__((ext_vector_type(8))) short bf16x8;
typedef __attribute__((ext_vector_type(4))) float f32x4;
typedef __attribute__((ext_vector_type(8))) unsigned short ushort8;
typedef __attribute__((address_space(3))) unsigned char lds_byte;
typedef __attribute__((address_space(1))) unsigned char glb_byte;

__device__ __forceinline__ unsigned short f2bf(float f) {
  unsigned int u = __float_as_uint(f);
  u = (u + 0x7FFFu + ((u >> 16) & 1u)) >> 16;
  return (unsigned short)u;
}
__device__ __forceinline__ float bf2f(unsigned short h) {
  return __uint_as_float(((unsigned int)h) << 16);
}
__device__ __forceinline__ void gload_lds16(const unsigned short* g, unsigned short* l) {
  __builtin_amdgcn_global_load_lds((const glb_byte*)g, (lds_byte*)l, 16, 0, 0);
}

// ---------------- prep mega-kernel: converts + BfT + GT + zero-init --------
// blocks [0,16):    GT[o][e] = sum_h Cw[e][h] * W[h][o]   (fp32, exact routing)
// block  16:        zero loss/counts/cursor
// blocks [17,145):  BfT[k][e][a] = (k==0 ? (e==a) : Brest[k-1][a][e])  (bf16)
// blocks [145,..):  fp32->bf16 converts of X1, X0, U, W, A
__global__ __launch_bounds__(256) void prep_k(
    const float* __restrict__ X1, const float* __restrict__ X0,
    const float* __restrict__ U, const float* __restrict__ W,
    const float* __restrict__ Aall, const float* __restrict__ Brest,
    const float* __restrict__ Cw,
    unsigned short* __restrict__ X1bf, unsigned short* __restrict__ X0bf,
    unsigned short* __restrict__ Ubf, unsigned short* __restrict__ Wbf,
    unsigned short* __restrict__ Abf, unsigned short* __restrict__ BfT,
    float* __restrict__ GT, float* __restrict__ loss,
    int* __restrict__ counts, int* __restrict__ cursor) {
  const int b = blockIdx.x, tid = threadIdx.x;
  if (b < 16) {  // GT
    int e = b >> 1;
    int o = ((b & 1) << 8) + tid;
    float s = 0.f;
    for (int h = 0; h < ENCD; h++) s += Cw[e * ENCD + h] * W[(size_t)h * OBSD + o];
    GT[o * KEXP + e] = s;
    return;
  }
  if (b == 16) {
    if (tid == 0) *loss = 0.f;
    if (tid < KEXP) { counts[tid] = 0; cursor[tid] = 0; }
    return;
  }
  if (b < 145) {  // BfT: 8 consecutive a's per thread
    int i0 = (b - 17) * 2048 + tid * 8;
    int k = i0 >> 15;             // / (512*64)
    int rem = i0 & 32767;
    int e = rem >> 6, a0 = rem & 63;
    ushort8 r;
#pragma unroll
    for (int j = 0; j < 8; j++) {
      int a = a0 + j;
      float v = (k == 0) ? ((e == a) ? 1.f : 0.f)
                         : Brest[((size_t)(k - 1) * ACTD + a) * ENCD + e];
      r[j] = f2bf(v);
    }
    *(ushort8*)&BfT[i0] = r;
    return;
  }
  // converts
  int cb = b - 145;
  const float* src;
  unsigned short* dst;
  int base;
  if (cb < 4096)      { src = X1;   dst = X1bf; base = cb; }
  else if (cb < 8192) { src = X0;   dst = X0bf; base = cb - 4096; }
  else if (cb < 8704) { src = U;    dst = Ubf;  base = cb - 8192; }
  else if (cb < 8832) { src = W;    dst = Wbf;  base = cb - 8704; }
  else                { src = Aall; dst = Abf;  base = cb - 8832; }
  size_t i = ((size_t)base * 256 + tid);
  const float4* s4 = (const float4*)src + i * 2;
  float4 a = s4[0], c = s4[1];
  ushort8 r;
  r[0] = f2bf(a.x); r[1] = f2bf(a.y); r[2] = f2bf(a.z); r[3] = f2bf(a.w);
  r[4] = f2bf(c.x); r[5] = f2bf(c.y); r[6] = f2bf(c.z); r[7] = f2bf(c.w);
  *(ushort8*)&dst[i * 8] = r;
}

// ---------------- routing: one THREAD per row, GT via scalar loads ---------
__global__ __launch_bounds__(128) void routing_k(
    const float* __restrict__ X0, const float* __restrict__ GT,
    const float* __restrict__ Cb, int* __restrict__ inds,
    int* __restrict__ counts) {
  __shared__ int lhist[KEXP];
  const int tid = threadIdx.x;
  if (tid < KEXP) lhist[tid] = 0;
  __syncthreads();
  const int n = blockIdx.x * 128 + tid;
  const float4* xr = (const float4*)(X0 + (size_t)n * OBSD);
  float acc[KEXP] = {};
  for (int h4 = 0; h4 < OBSD / 4; h4++) {
    float4 x = xr[h4];
    float xv[4] = {x.x, x.y, x.z, x.w};
#pragma unroll
    for (int j = 0; j < 4; j++) {
      const float* g = GT + (h4 * 4 + j) * KEXP;  // wave-uniform -> s_load
#pragma unroll
      for (int e = 0; e < KEXP; e++) acc[e] += xv[j] * g[e];
    }
  }
  int best = 0;
  float bv = acc[0] + Cb[0];
#pragma unroll
  for (int e = 1; e < KEXP; e++) {
    float v = acc[e] + Cb[e];
    if (v > bv) { bv = v; best = e; }  // strict >: first max wins (jnp.argmax)
  }
  inds[n] = best;
  atomicAdd(&lhist[best], 1);
  __syncthreads();
  if (tid < KEXP) atomicAdd(&counts[tid], lhist[tid]);
}

__global__ void prefix_k(const int* __restrict__ counts, int* __restrict__ cursor,
                         int* __restrict__ starts) {
  if (threadIdx.x == 0 && blockIdx.x == 0) {
    int s = 0;
    for (int k = 0; k < KEXP; k++) { starts[k] = s; cursor[k] = s; s += counts[k]; }
    starts[KEXP] = s;
  }
}

// ---------------- scatter: LDS histogram, 8 global atomics per block -------
__global__ __launch_bounds__(256) void scatter_k(
    const int* __restrict__ inds, int* __restrict__ cursor,
    int* __restrict__ rowlist) {
  __shared__ int lhist[KEXP], lbase[KEXP];
  const int tid = threadIdx.x;
  if (tid < KEXP) lhist[tid] = 0;
  __syncthreads();
  const int n = blockIdx.x * 256 + tid;
  const int r = inds[n];
  const int lpos = atomicAdd(&lhist[r], 1);
  __syncthreads();
  if (tid < KEXP) lbase[tid] = atomicAdd(&cursor[tid], lhist[tid]);
  __syncthreads();
  rowlist[lbase[r] + lpos] = n;
}

// ---------------- encoder MFMA GEMM: E = X @ W^T (bf16 in, bf16 out) -------
__global__ __launch_bounds__(256, 2) void enc_mfma_k(
    const unsigned short* __restrict__ X1bf, const unsigned short* __restrict__ X0bf,
    const unsigned short* __restrict__ Wbf, unsigned short* __restrict__ X1ebf,
    unsigned short* __restrict__ X0ebf) {
  __shared__ unsigned short As[128 * 32];
  __shared__ unsigned short Bs[128 * 32];
  const int tid = threadIdx.x;
  const int nxy = 512, nwg = 1024, cpx = nwg >> 3;
  int bid = blockIdx.x + 4 * (blockIdx.y + 128 * blockIdx.z);
  int lid = (bid & 7) * cpx + (bid >> 3);
  int lz = lid / nxy;
  int rem = lid - lz * nxy;
  int col0 = (rem & 3) * 128;
  int row0 = (rem >> 2) * 128;
  const unsigned short* X = lz ? X0bf : X1bf;
  unsigned short* E = lz ? X0ebf : X1ebf;

  const int lane = tid & 63, w = tid >> 6;
  const int wr = w >> 1, wc = w & 1;
  const int gslot = ((tid & 3) ^ ((tid >> 3) & 3)) * 8;
  const int srow = tid >> 2;
  const int ldsoff = tid * 8;
  const int rslot = ((lane >> 4) ^ (((lane & 15) >> 1) & 3)) * 8;
  const int arow = wr * 64 + (lane & 15);
  const int brow = wc * 64 + (lane & 15);

  f32x4 acc[4][4] = {};
  for (int k0 = 0; k0 < OBSD; k0 += 32) {
    gload_lds16(X + (size_t)(row0 + srow) * OBSD + k0 + gslot, &As[ldsoff]);
    gload_lds16(X + (size_t)(row0 + 64 + srow) * OBSD + k0 + gslot, &As[2048 + ldsoff]);
    gload_lds16(Wbf + (size_t)(col0 + srow) * OBSD + k0 + gslot, &Bs[ldsoff]);
    gload_lds16(Wbf + (size_t)(col0 + 64 + srow) * OBSD + k0 + gslot, &Bs[2048 + ldsoff]);
    __syncthreads();
    bf16x8 af[4], bfr[4];
#pragma unroll
    for (int m = 0; m < 4; m++) af[m] = *(const bf16x8*)&As[(arow + m * 16) * 32 + rslot];
#pragma unroll
    for (int n = 0; n < 4; n++) bfr[n] = *(const bf16x8*)&Bs[(brow + n * 16) * 32 + rslot];
#pragma unroll
    for (int m = 0; m < 4; m++)
#pragma unroll
      for (int n = 0; n < 4; n++)
        acc[m][n] = __builtin_amdgcn_mfma_f32_16x16x32_bf16(af[m], bfr[n], acc[m][n], 0, 0, 0);
    __syncthreads();
  }
#pragma unroll
  for (int m = 0; m < 4; m++) {
    int rg = row0 + wr * 64 + m * 16 + (lane >> 4) * 4;
#pragma unroll
    for (int n = 0; n < 4; n++) {
      int cg = col0 + wc * 64 + n * 16 + (lane & 15);
#pragma unroll
      for (int r = 0; r < 4; r++) E[(size_t)(rg + r) * ENCD + cg] = f2bf(acc[m][n][r]);
    }
  }
}

// ---------------- grouped MFMA GEMM + fused (X1e - pred)^2 -----------------
__global__ __launch_bounds__(256, 2) void grouped_mfma_k(
    const unsigned short* __restrict__ X0ebf, const unsigned short* __restrict__ X1ebf,
    const unsigned short* __restrict__ Ubf, const unsigned short* __restrict__ Abf,
    const unsigned short* __restrict__ BfTbf, const int* __restrict__ rowlist,
    const int* __restrict__ starts, float* __restrict__ loss) {
  const int tid = threadIdx.x;
  const int nxy = 512, nwg = 4096, cpx = nwg >> 3;
  int bid = blockIdx.x + 4 * (blockIdx.y + 128 * blockIdx.z);
  int lid = (bid & 7) * cpx + (bid >> 3);
  int k = lid / nxy;
  int rem = lid - k * nxy;
  int col0 = (rem & 3) * 128;
  int tile = rem >> 2;

  const int start = starts[k];
  const int cnt = starts[k + 1] - start;
  if (tile * 128 >= cnt) return;

  __shared__ unsigned short As[128 * 32];
  __shared__ unsigned short Bs[128 * 32];
  __shared__ int ridx[128];
  __shared__ float red[4];

  if (tid < 128) {
    int p = tile * 128 + tid;
    ridx[tid] = rowlist[start + (p < cnt ? p : 0)];
  }
  __syncthreads();

  const int lane = tid & 63, w = tid >> 6;
  const int wr = w >> 1, wc = w & 1;
  const int gslot = ((tid & 3) ^ ((tid >> 3) & 3)) * 8;
  const int srow = tid >> 2;
  const int ldsoff = tid * 8;
  const int rslot = ((lane >> 4) ^ (((lane & 15) >> 1) & 3)) * 8;
  const int arow = wr * 64 + (lane & 15);
  const int brow = wc * 64 + (lane & 15);
  const int rn0 = ridx[srow];
  const int rn1 = ridx[64 + srow];

  f32x4 acc[4][4] = {};
  const unsigned short* Ak = Abf + (size_t)k * ENCD * ENCD;
  for (int k0 = 0; k0 < ENCD; k0 += 32) {
    gload_lds16(X0ebf + (size_t)rn0 * ENCD + k0 + gslot, &As[ldsoff]);
    gload_lds16(X0ebf + (size_t)rn1 * ENCD + k0 + gslot, &As[2048 + ldsoff]);
    gload_lds16(Ak + (size_t)(col0 + srow) * ENCD + k0 + gslot, &Bs[ldsoff]);
    gload_lds16(Ak + (size_t)(col0 + 64 + srow) * ENCD + k0 + gslot, &Bs[2048 + ldsoff]);
    __syncthreads();
    bf16x8 af[4], bfr[4];
#pragma unroll
    for (int m = 0; m < 4; m++) af[m] = *(const bf16x8*)&As[(arow + m * 16) * 32 + rslot];
#pragma unroll
    for (int n = 0; n < 4; n++) bfr[n] = *(const bf16x8*)&Bs[(brow + n * 16) * 32 + rslot];
#pragma unroll
    for (int m = 0; m < 4; m++)
#pragma unroll
      for (int n = 0; n < 4; n++)
        acc[m][n] = __builtin_amdgcn_mfma_f32_16x16x32_bf16(af[m], bfr[n], acc[m][n], 0, 0, 0);
    __syncthreads();
  }
  const unsigned short* BfTk = BfTbf + (size_t)k * ENCD * ACTD;
  for (int a0 = 0; a0 < ACTD; a0 += 32) {
    gload_lds16(Ubf + (size_t)rn0 * ACTD + a0 + gslot, &As[ldsoff]);
    gload_lds16(Ubf + (size_t)rn1 * ACTD + a0 + gslot, &As[2048 + ldsoff]);
    gload_lds16(BfTk + (size_t)(col0 + srow) * ACTD + a0 + gslot, &Bs[ldsoff]);
    gload_lds16(BfTk + (size_t)(col0 + 64 + srow) * ACTD + a0 + gslot, &Bs[2048 + ldsoff]);
    __syncthreads();
    bf16x8 af[4], bfr[4];
#pragma unroll
    for (int m = 0; m < 4; m++) af[m] = *(const bf16x8*)&As[(arow + m * 16) * 32 + rslot];
#pragma unroll
    for (int n = 0; n < 4; n++) bfr[n] = *(const bf16x8*)&Bs[(brow + n * 16) * 32 + rslot];
#pragma unroll
    for (int m = 0; m < 4; m++)
#pragma unroll
      for (int n = 0; n < 4; n++)
        acc[m][n] = __builtin_amdgcn_mfma_f32_16x16x32_bf16(af[m], bfr[n], acc[m][n], 0, 0, 0);
    __syncthreads();
  }
  float sq = 0.f;
#pragma unroll
  for (int m = 0; m < 4; m++) {
    int lr0 = wr * 64 + m * 16 + (lane >> 4) * 4;
#pragma unroll
    for (int n = 0; n < 4; n++) {
      int cg = col0 + wc * 64 + n * 16 + (lane & 15);
#pragma unroll
      for (int r = 0; r < 4; r++) {
        int lr = lr0 + r;
        if (tile * 128 + lr < cnt) {
          float x1 = bf2f(X1ebf[(size_t)ridx[lr] * ENCD + cg]);
          float d = x1 - acc[m][n][r];
          sq += d * d;
        }
      }
    }
  }
#pragma unroll
  for (int off = 32; off > 0; off >>= 1) sq += __shfl_xor(sq, off, 64);
  if (lane == 0) red[w] = sq;
  __syncthreads();
  if (tid == 0) atomicAdd(loss, red[0] + red[1] + red[2] + red[3]);
}

__global__ void finalize_k(const float* __restrict__ loss, float* __restrict__ out) {
  if (threadIdx.x == 0 && blockIdx.x == 0)
    out[0] = loss[0] * (1.0f / ((float)ENCD * (float)NROWS));
}

extern "C" void kernel_launch(void* const* d_in, const int* in_sizes, int n_in,
                              void* d_out, int out_size, void* d_ws, size_t ws_size,
                              hipStream_t stream) {
  const float* X1 = (const float*)d_in[0];
  const float* X0 = (const float*)d_in[1];
  const float* U = (const float*)d_in[2];
  const float* W = (const float*)d_in[3];
  const float* Aall = (const float*)d_in[4];
  const float* Brest = (const float*)d_in[5];
  const float* Cw = (const float*)d_in[6];
  const float* Cb = (const float*)d_in[7];
  float* out = (float*)d_out;

  char* p = (char*)d_ws;
  auto alloc = [&](size_t bytes) { char* r = p; p += (bytes + 255) & ~(size_t)255; return r; };
  unsigned short* X1bf = (unsigned short*)alloc((size_t)NROWS * OBSD * 2);
  unsigned short* X0bf = (unsigned short*)alloc((size_t)NROWS * OBSD * 2);
  unsigned short* Ubf = (unsigned short*)alloc((size_t)NROWS * ACTD * 2);
  unsigned short* Wbf = (unsigned short*)alloc((size_t)ENCD * OBSD * 2);
  unsigned short* Abf = (unsigned short*)alloc((size_t)KEXP * ENCD * ENCD * 2);
  unsigned short* BfT = (unsigned short*)alloc((size_t)KEXP * ENCD * ACTD * 2);
  unsigned short* X1ebf = (unsigned short*)alloc((size_t)NROWS * ENCD * 2);
  unsigned short* X0ebf = (unsigned short*)alloc((size_t)NROWS * ENCD * 2);
  float* GT = (float*)alloc(KEXP * OBSD * 4);
  float* loss = (float*)alloc(256);
  int* inds = (int*)alloc(NROWS * 4);
  int* rowlist = (int*)alloc(NROWS * 4);
  int* counts = (int*)alloc(64);
  int* cursor = (int*)alloc(64);
  int* starts = (int*)alloc(64);

  prep_k<<<10001, 256, 0, stream>>>(X1, X0, U, W, Aall, Brest, Cw,
                                    X1bf, X0bf, Ubf, Wbf, Abf, BfT,
                                    GT, loss, counts, cursor);
  routing_k<<<NROWS / 128, 128, 0, stream>>>(X0, GT, Cb, inds, counts);
  prefix_k<<<1, 1, 0, stream>>>(counts, cursor, starts);
  scatter_k<<<NROWS / 256, 256, 0, stream>>>(inds, cursor, rowlist);

  enc_mfma_k<<<dim3(4, 128, 2), 256, 0, stream>>>(X1bf, X0bf, Wbf, X1ebf, X0ebf);
  grouped_mfma_k<<<dim3(4, 128, 8), 256, 0, stream>>>(X0ebf, X1ebf, Ubf, Abf, BfT,
                                                      rowlist, starts, loss);
  finalize_k<<<1, 64, 0, stream>>>(loss, out);
}

// Round 4
// 115.308 us; speedup vs baseline: 7.4014x; 1.0965x over previous
//
#include <hip/hip_runtime.h>

#define NROWS 16384
#define OBSD 512
#define ENCD 512
#define ACTD 64
#define KEXP 8

typedef __attribute__((ext_vector_type(8))) short bf16x8;
typedef __attribute__((ext_vector_type(4))) float f32x4;
typedef __attribute__((address_space(3))) unsigned char lds_byte;
typedef __attribute__((address_space(1))) unsigned char glb_byte;

__device__ __forceinline__ unsigned short f2bf(float f) {
  unsigned int u = __float_as_uint(f);
  u = (u + 0x7FFFu + ((u >> 16) & 1u)) >> 16;
  return (unsigned short)u;
}
__device__ __forceinline__ float bf2f(unsigned short h) {
  return __uint_as_float(((unsigned int)h) << 16);
}
__device__ __forceinline__ unsigned int cvtpk(float lo, float hi) {
  unsigned int r;
  asm("v_cvt_pk_bf16_f32 %0, %1, %2" : "=v"(r) : "v"(lo), "v"(hi));
  return r;
}
__device__ __forceinline__ void gload_lds16(const unsigned short* g, unsigned short* l) {
  __builtin_amdgcn_global_load_lds((const glb_byte*)g, (lds_byte*)l, 16, 0, 0);
}

// ---------------- prep2: GT + zero + BfT (tile transpose) + U/A converts ---
// b [0,64):    GT[o][e] = sum_h Cw[e][h]*W[h][o], 4-way h-split + LDS reduce
// b 64:        zero loss/counts/cursor
// b 65:        BfT expert 0 = identity
// b [66,122):  BfT[k][e][a] = Brest[k-1][a][e] via 64x64 LDS transpose
// b [122,3194): dense float4->bf16x4 converts of U then A
__global__ __launch_bounds__(256) void prep2_k(
    const float* __restrict__ U, const float* __restrict__ W,
    const float* __restrict__ Aall, const float* __restrict__ Brest,
    const float* __restrict__ Cw,
    unsigned short* __restrict__ Ubf, unsigned short* __restrict__ Abf,
    unsigned short* __restrict__ BfT, float* __restrict__ GT,
    float* __restrict__ loss, int* __restrict__ counts, int* __restrict__ cursor) {
  const int b = blockIdx.x, tid = threadIdx.x;
  if (b < 64) {  // GT
    __shared__ float red[4][64];
    int e = b >> 3, o0 = (b & 7) * 64;
    int o = tid & 63, hg = tid >> 6;
    float s = 0.f;
#pragma unroll 8
    for (int h = hg * 128; h < hg * 128 + 128; h++)
      s += Cw[e * ENCD + h] * W[(size_t)h * OBSD + o0 + o];
    red[hg][o] = s;
    __syncthreads();
    if (tid < 64)
      GT[(o0 + tid) * KEXP + e] = red[0][tid] + red[1][tid] + red[2][tid] + red[3][tid];
    return;
  }
  if (b == 64) {
    if (tid == 0) *loss = 0.f;
    if (tid < KEXP) { counts[tid] = 0; cursor[tid] = 0; }
    return;
  }
  if (b == 65) {  // expert-0 identity: BfT[0][e][a] = (e==a)
    for (int j = 0; j < 16; j++) {
      int i8 = j * 256 + tid;       // 4096 groups of 8 a's
      int e = i8 >> 3, a0 = (i8 & 7) * 8;
      unsigned int w0 = 0, w1 = 0, w2 = 0, w3 = 0;
      if (e >= a0 && e < a0 + 8) {
        unsigned int bits = 0x3F80u << ((e & 1) * 16);
        if ((e - a0) >> 1 == 0) w0 = bits;
        else if ((e - a0) >> 1 == 1) w1 = bits;
        else if ((e - a0) >> 1 == 2) w2 = bits;
        else w3 = bits;
      }
      uint4 v = {w0, w1, w2, w3};
      *(uint4*)&BfT[(size_t)i8 * 8] = v;
    }
    return;
  }
  if (b < 122) {  // BfT transpose for experts 1..7
    __shared__ float tile[64][65];
    int t = b - 66;
    int k = (t >> 3);           // 0..6 -> expert k+1
    int e0 = (t & 7) * 64;
    const float* src = Brest + (size_t)k * ACTD * ENCD + e0;
#pragma unroll
    for (int j = 0; j < 16; j++) {
      int idx = j * 256 + tid;
      int a = idx >> 6, e = idx & 63;
      tile[a][e] = src[(size_t)a * ENCD + e];  // lanes: consecutive e -> coalesced
    }
    __syncthreads();
    unsigned short* dst = BfT + ((size_t)(k + 1) * ENCD + e0) * ACTD;
#pragma unroll
    for (int j = 0; j < 16; j++) {
      int idx = j * 256 + tid;
      int e = idx >> 6, a = idx & 63;
      dst[(size_t)e * ACTD + a] = f2bf(tile[a][e]);  // lanes: consecutive a
    }
    return;
  }
  // converts: U (1024 blocks) then A (2048 blocks); 4 floats/thread, dense
  int cb = b - 122;
  const float* src;
  unsigned short* dst;
  size_t i;
  if (cb < 1024) { src = U; dst = Ubf; i = (size_t)cb * 256 + tid; }
  else           { src = Aall; dst = Abf; i = (size_t)(cb - 1024) * 256 + tid; }
  float4 v = ((const float4*)src)[i];
  uint2 r = {cvtpk(v.x, v.y), cvtpk(v.z, v.w)};
  *(uint2*)&dst[i * 4] = r;
}

// ---------------- routing: one THREAD per row, GT via scalar loads ---------
__global__ __launch_bounds__(128) void routing_k(
    const float* __restrict__ X0, const float* __restrict__ GT,
    const float* __restrict__ Cb, int* __restrict__ inds,
    int* __restrict__ counts) {
  __shared__ int lhist[KEXP];
  const int tid = threadIdx.x;
  if (tid < KEXP) lhist[tid] = 0;
  __syncthreads();
  const int n = blockIdx.x * 128 + tid;
  const float4* xr = (const float4*)(X0 + (size_t)n * OBSD);
  float acc[KEXP] = {};
  for (int h4 = 0; h4 < OBSD / 4; h4++) {
    float4 x = xr[h4];
    float xv[4] = {x.x, x.y, x.z, x.w};
#pragma unroll
    for (int j = 0; j < 4; j++) {
      const float* g = GT + (h4 * 4 + j) * KEXP;  // wave-uniform -> s_load
#pragma unroll
      for (int e = 0; e < KEXP; e++) acc[e] += xv[j] * g[e];
    }
  }
  int best = 0;
  float bv = acc[0] + Cb[0];
#pragma unroll
  for (int e = 1; e < KEXP; e++) {
    float v = acc[e] + Cb[e];
    if (v > bv) { bv = v; best = e; }  // strict >: first max wins (jnp.argmax)
  }
  inds[n] = best;
  atomicAdd(&lhist[best], 1);
  __syncthreads();
  if (tid < KEXP) atomicAdd(&counts[tid], lhist[tid]);
}

__global__ void prefix_k(const int* __restrict__ counts, int* __restrict__ cursor,
                         int* __restrict__ starts) {
  if (threadIdx.x == 0 && blockIdx.x == 0) {
    int s = 0;
    for (int k = 0; k < KEXP; k++) { starts[k] = s; cursor[k] = s; s += counts[k]; }
    starts[KEXP] = s;
  }
}

__global__ __launch_bounds__(256) void scatter_k(
    const int* __restrict__ inds, int* __restrict__ cursor,
    int* __restrict__ rowlist) {
  __shared__ int lhist[KEXP], lbase[KEXP];
  const int tid = threadIdx.x;
  if (tid < KEXP) lhist[tid] = 0;
  __syncthreads();
  const int n = blockIdx.x * 256 + tid;
  const int r = inds[n];
  const int lpos = atomicAdd(&lhist[r], 1);
  __syncthreads();
  if (tid < KEXP) lbase[tid] = atomicAdd(&cursor[tid], lhist[tid]);
  __syncthreads();
  rowlist[lbase[r] + lpos] = n;
}

// ---------------- encoder MFMA GEMM: E = X @ W^T (fp32 in, bf16 out) -------
// reg-staged fp32 -> cvt_pk bf16 -> swizzled LDS. Swapped-operand MFMA so the
// epilogue packs 4 consecutive cols per lane (dwordx2 stores).
__global__ __launch_bounds__(256, 3) void enc_mfma_k(
    const float* __restrict__ X1, const float* __restrict__ X0,
    const float* __restrict__ W, unsigned short* __restrict__ X1e,
    unsigned short* __restrict__ X0e) {
  __shared__ unsigned short As[128 * 32];
  __shared__ unsigned short Bs[128 * 32];
  const int tid = threadIdx.x;
  const int bid = blockIdx.x;               // 1024 blocks, %8==0 -> bijective
  const int lid = (bid & 7) * 128 + (bid >> 3);
  const int lz = lid >> 9;
  const int rem = lid & 511;
  const int col0 = (rem & 3) * 128;
  const int row0 = (rem >> 2) * 128;
  const float* X = lz ? X0 : X1;
  unsigned short* E = lz ? X0e : X1e;

  const int lane = tid & 63, w = tid >> 6;
  const int wr = w >> 1, wc = w & 1;
  // staging: thread owns 16 consecutive floats of one row (row tid>>1)
  const int srow = tid >> 1, sj = tid & 1;
  const int swz = (srow >> 1) & 3;
  const int wo0 = srow * 32 + ((2 * sj) ^ swz) * 8;       // swizzled 16B slots
  const int wo1 = srow * 32 + ((2 * sj + 1) ^ swz) * 8;
  const int rslot = ((lane >> 4) ^ (((lane & 15) >> 1) & 3)) * 8;
  const int arow = wr * 64 + (lane & 15);
  const int brow = wc * 64 + (lane & 15);
  const float* pX = X + (size_t)(row0 + srow) * OBSD + sj * 16;
  const float* pW = W + (size_t)(col0 + srow) * OBSD + sj * 16;

  f32x4 acc[4][4] = {};
  for (int k0 = 0; k0 < OBSD; k0 += 32) {
    float4 a0 = *(const float4*)(pX + k0);
    float4 a1 = *(const float4*)(pX + k0 + 4);
    float4 a2 = *(const float4*)(pX + k0 + 8);
    float4 a3 = *(const float4*)(pX + k0 + 12);
    float4 b0 = *(const float4*)(pW + k0);
    float4 b1 = *(const float4*)(pW + k0 + 4);
    float4 b2 = *(const float4*)(pW + k0 + 8);
    float4 b3 = *(const float4*)(pW + k0 + 12);
    uint4 pa0 = {cvtpk(a0.x, a0.y), cvtpk(a0.z, a0.w), cvtpk(a1.x, a1.y), cvtpk(a1.z, a1.w)};
    uint4 pa1 = {cvtpk(a2.x, a2.y), cvtpk(a2.z, a2.w), cvtpk(a3.x, a3.y), cvtpk(a3.z, a3.w)};
    uint4 pb0 = {cvtpk(b0.x, b0.y), cvtpk(b0.z, b0.w), cvtpk(b1.x, b1.y), cvtpk(b1.z, b1.w)};
    uint4 pb1 = {cvtpk(b2.x, b2.y), cvtpk(b2.z, b2.w), cvtpk(b3.x, b3.y), cvtpk(b3.z, b3.w)};
    *(uint4*)&As[wo0] = pa0;
    *(uint4*)&As[wo1] = pa1;
    *(uint4*)&Bs[wo0] = pb0;
    *(uint4*)&Bs[wo1] = pb1;
    __syncthreads();
    bf16x8 af[4], bfr[4];
#pragma unroll
    for (int m = 0; m < 4; m++) af[m] = *(const bf16x8*)&As[(arow + m * 16) * 32 + rslot];
#pragma unroll
    for (int n = 0; n < 4; n++) bfr[n] = *(const bf16x8*)&Bs[(brow + n * 16) * 32 + rslot];
#pragma unroll
    for (int m = 0; m < 4; m++)
#pragma unroll
      for (int n = 0; n < 4; n++)  // swapped: D row<->W(col of E), col<->X(row of E)
        acc[m][n] = __builtin_amdgcn_mfma_f32_16x16x32_bf16(bfr[n], af[m], acc[m][n], 0, 0, 0);
    __syncthreads();
  }
#pragma unroll
  for (int m = 0; m < 4; m++) {
    int rowg = row0 + wr * 64 + m * 16 + (lane & 15);
#pragma unroll
    for (int n = 0; n < 4; n++) {
      int colg = col0 + wc * 64 + n * 16 + (lane >> 4) * 4;
      uint2 v = {cvtpk(acc[m][n][0], acc[m][n][1]), cvtpk(acc[m][n][2], acc[m][n][3])};
      *(uint2*)&E[(size_t)rowg * ENCD + colg] = v;
    }
  }
}

// ---------------- grouped MFMA GEMM + fused (X1e - pred)^2 -----------------
__global__ __launch_bounds__(256, 2) void grouped_mfma_k(
    const unsigned short* __restrict__ X0ebf, const unsigned short* __restrict__ X1ebf,
    const unsigned short* __restrict__ Ubf, const unsigned short* __restrict__ Abf,
    const unsigned short* __restrict__ BfTbf, const int* __restrict__ rowlist,
    const int* __restrict__ starts, float* __restrict__ loss) {
  const int tid = threadIdx.x;
  const int bid = blockIdx.x;               // 4096 blocks
  const int lid = (bid & 7) * 512 + (bid >> 3);
  const int k = lid >> 9;
  const int rem = lid & 511;
  const int col0 = (rem & 3) * 128;
  const int tile = rem >> 2;

  const int start = starts[k];
  const int cnt = starts[k + 1] - start;
  if (tile * 128 >= cnt) return;

  __shared__ unsigned short As[128 * 32];
  __shared__ unsigned short Bs[128 * 32];
  __shared__ int ridx[128];
  __shared__ float red[4];

  if (tid < 128) {
    int p = tile * 128 + tid;
    ridx[tid] = rowlist[start + (p < cnt ? p : 0)];
  }
  __syncthreads();

  const int lane = tid & 63, w = tid >> 6;
  const int wr = w >> 1, wc = w & 1;
  const int gslot = ((tid & 3) ^ ((tid >> 3) & 3)) * 8;
  const int srow = tid >> 2;
  const int ldsoff = tid * 8;
  const int rslot = ((lane >> 4) ^ (((lane & 15) >> 1) & 3)) * 8;
  const int arow = wr * 64 + (lane & 15);
  const int brow = wc * 64 + (lane & 15);
  const int rn0 = ridx[srow];
  const int rn1 = ridx[64 + srow];

  f32x4 acc[4][4] = {};
  const unsigned short* Ak = Abf + (size_t)k * ENCD * ENCD;
  for (int k0 = 0; k0 < ENCD; k0 += 32) {
    gload_lds16(X0ebf + (size_t)rn0 * ENCD + k0 + gslot, &As[ldsoff]);
    gload_lds16(X0ebf + (size_t)rn1 * ENCD + k0 + gslot, &As[2048 + ldsoff]);
    gload_lds16(Ak + (size_t)(col0 + srow) * ENCD + k0 + gslot, &Bs[ldsoff]);
    gload_lds16(Ak + (size_t)(col0 + 64 + srow) * ENCD + k0 + gslot, &Bs[2048 + ldsoff]);
    __syncthreads();
    bf16x8 af[4], bfr[4];
#pragma unroll
    for (int m = 0; m < 4; m++) af[m] = *(const bf16x8*)&As[(arow + m * 16) * 32 + rslot];
#pragma unroll
    for (int n = 0; n < 4; n++) bfr[n] = *(const bf16x8*)&Bs[(brow + n * 16) * 32 + rslot];
#pragma unroll
    for (int m = 0; m < 4; m++)
#pragma unroll
      for (int n = 0; n < 4; n++)
        acc[m][n] = __builtin_amdgcn_mfma_f32_16x16x32_bf16(bfr[n], af[m], acc[m][n], 0, 0, 0);
    __syncthreads();
  }
  const unsigned short* BfTk = BfTbf + (size_t)k * ENCD * ACTD;
  for (int a0 = 0; a0 < ACTD; a0 += 32) {
    gload_lds16(Ubf + (size_t)rn0 * ACTD + a0 + gslot, &As[ldsoff]);
    gload_lds16(Ubf + (size_t)rn1 * ACTD + a0 + gslot, &As[2048 + ldsoff]);
    gload_lds16(BfTk + (size_t)(col0 + srow) * ACTD + a0 + gslot, &Bs[ldsoff]);
    gload_lds16(BfTk + (size_t)(col0 + 64 + srow) * ACTD + a0 + gslot, &Bs[2048 + ldsoff]);
    __syncthreads();
    bf16x8 af[4], bfr[4];
#pragma unroll
    for (int m = 0; m < 4; m++) af[m] = *(const bf16x8*)&As[(arow + m * 16) * 32 + rslot];
#pragma unroll
    for (int n = 0; n < 4; n++) bfr[n] = *(const bf16x8*)&Bs[(brow + n * 16) * 32 + rslot];
#pragma unroll
    for (int m = 0; m < 4; m++)
#pragma unroll
      for (int n = 0; n < 4; n++)
        acc[m][n] = __builtin_amdgcn_mfma_f32_16x16x32_bf16(bfr[n], af[m], acc[m][n], 0, 0, 0);
    __syncthreads();
  }
  // fused epilogue: lane owns row m*16+(lane&15), 4 consecutive cols per (m,n)
  float sq = 0.f;
#pragma unroll
  for (int m = 0; m < 4; m++) {
    int lr = wr * 64 + m * 16 + (lane & 15);
    bool valid = (tile * 128 + lr) < cnt;
    const unsigned short* xrow = X1ebf + (size_t)ridx[lr] * ENCD;
#pragma unroll
    for (int n = 0; n < 4; n++) {
      int cg = col0 + wc * 64 + n * 16 + (lane >> 4) * 4;
      if (valid) {
        ushort4 x4 = *(const ushort4*)&xrow[cg];
        float d0 = bf2f(x4.x) - acc[m][n][0];
        float d1 = bf2f(x4.y) - acc[m][n][1];
        float d2 = bf2f(x4.z) - acc[m][n][2];
        float d3 = bf2f(x4.w) - acc[m][n][3];
        sq += d0 * d0 + d1 * d1 + d2 * d2 + d3 * d3;
      }
    }
  }
#pragma unroll
  for (int off = 32; off > 0; off >>= 1) sq += __shfl_xor(sq, off, 64);
  if (lane == 0) red[w] = sq;
  __syncthreads();
  if (tid == 0) atomicAdd(loss, red[0] + red[1] + red[2] + red[3]);
}

__global__ void finalize_k(const float* __restrict__ loss, float* __restrict__ out) {
  if (threadIdx.x == 0 && blockIdx.x == 0)
    out[0] = loss[0] * (1.0f / ((float)ENCD * (float)NROWS));
}

extern "C" void kernel_launch(void* const* d_in, const int* in_sizes, int n_in,
                              void* d_out, int out_size, void* d_ws, size_t ws_size,
                              hipStream_t stream) {
  const float* X1 = (const float*)d_in[0];
  const float* X0 = (const float*)d_in[1];
  const float* U = (const float*)d_in[2];
  const float* W = (const float*)d_in[3];
  const float* Aall = (const float*)d_in[4];
  const float* Brest = (const float*)d_in[5];
  const float* Cw = (const float*)d_in[6];
  const float* Cb = (const float*)d_in[7];
  float* out = (float*)d_out;

  char* p = (char*)d_ws;
  auto alloc = [&](size_t bytes) { char* r = p; p += (bytes + 255) & ~(size_t)255; return r; };
  unsigned short* Ubf = (unsigned short*)alloc((size_t)NROWS * ACTD * 2);
  unsigned short* Abf = (unsigned short*)alloc((size_t)KEXP * ENCD * ENCD * 2);
  unsigned short* BfT = (unsigned short*)alloc((size_t)KEXP * ENCD * ACTD * 2);
  unsigned short* X1ebf = (unsigned short*)alloc((size_t)NROWS * ENCD * 2);
  unsigned short* X0ebf = (unsigned short*)alloc((size_t)NROWS * ENCD * 2);
  float* GT = (float*)alloc(KEXP * OBSD * 4);
  float* loss = (float*)alloc(256);
  int* inds = (int*)alloc(NROWS * 4);
  int* rowlist = (int*)alloc(NROWS * 4);
  int* counts = (int*)alloc(64);
  int* cursor = (int*)alloc(64);
  int* starts = (int*)alloc(64);

  prep2_k<<<3194, 256, 0, stream>>>(U, W, Aall, Brest, Cw, Ubf, Abf, BfT, GT,
                                    loss, counts, cursor);
  routing_k<<<NROWS / 128, 128, 0, stream>>>(X0, GT, Cb, inds, counts);
  prefix_k<<<1, 1, 0, stream>>>(counts, cursor, starts);
  scatter_k<<<NROWS / 256, 256, 0, stream>>>(inds, cursor, rowlist);

  enc_mfma_k<<<1024, 256, 0, stream>>>(X1, X0, W, X1ebf, X0ebf);
  grouped_mfma_k<<<4096, 256, 0, stream>>>(X0ebf, X1ebf, Ubf, Abf, BfT,
                                           rowlist, starts, loss);
  finalize_k<<<1, 64, 0, stream>>>(loss, out);
}

// Round 6
// 114.468 us; speedup vs baseline: 7.4557x; 1.0073x over previous
//
#include <hip/hip_runtime.h>

#define NROWS 16384
#define OBSD 512
#define ENCD 512
#define ACTD 64
#define KEXP 8

typedef __attribute__((ext_vector_type(8))) short bf16x8;
typedef __attribute__((ext_vector_type(4))) float f32x4;
typedef __attribute__((address_space(3))) unsigned char lds_byte;
typedef __attribute__((address_space(1))) unsigned char glb_byte;

__device__ __forceinline__ unsigned short f2bf(float f) {
  unsigned int u = __float_as_uint(f);
  u = (u + 0x7FFFu + ((u >> 16) & 1u)) >> 16;
  return (unsigned short)u;
}
__device__ __forceinline__ float bf2f(unsigned short h) {
  return __uint_as_float(((unsigned int)h) << 16);
}
__device__ __forceinline__ unsigned int cvtpk(float lo, float hi) {
  unsigned int r;
  asm("v_cvt_pk_bf16_f32 %0, %1, %2" : "=v"(r) : "v"(lo), "v"(hi));
  return r;
}
__device__ __forceinline__ void gload_lds16(const unsigned short* g, unsigned short* l) {
  __builtin_amdgcn_global_load_lds((const glb_byte*)g, (lds_byte*)l, 16, 0, 0);
}

// ---------------- prep2: GT + zero + BfT (tile transpose) + U/A converts ---
__global__ __launch_bounds__(256) void prep2_k(
    const float* __restrict__ U, const float* __restrict__ W,
    const float* __restrict__ Aall, const float* __restrict__ Brest,
    const float* __restrict__ Cw,
    unsigned short* __restrict__ Ubf, unsigned short* __restrict__ Abf,
    unsigned short* __restrict__ BfT, float* __restrict__ GT,
    float* __restrict__ loss, int* __restrict__ counts, int* __restrict__ cursor) {
  const int b = blockIdx.x, tid = threadIdx.x;
  if (b < 64) {  // GT[o][e] = sum_h Cw[e][h]*W[h][o], 4-way h-split
    __shared__ float red[4][64];
    int e = b >> 3, o0 = (b & 7) * 64;
    int o = tid & 63, hg = tid >> 6;
    float s = 0.f;
#pragma unroll 8
    for (int h = hg * 128; h < hg * 128 + 128; h++)
      s += Cw[e * ENCD + h] * W[(size_t)h * OBSD + o0 + o];
    red[hg][o] = s;
    __syncthreads();
    if (tid < 64)
      GT[(o0 + tid) * KEXP + e] = red[0][tid] + red[1][tid] + red[2][tid] + red[3][tid];
    return;
  }
  if (b == 64) {
    if (tid == 0) *loss = 0.f;
    if (tid < KEXP) { counts[tid] = 0; cursor[tid] = 0; }
    return;
  }
  if (b == 65) {  // expert-0 identity: BfT[0][e][a] = (e==a)
    for (int j = 0; j < 16; j++) {
      int i8 = j * 256 + tid;
      int e = i8 >> 3, a0 = (i8 & 7) * 8;
      unsigned int w0 = 0, w1 = 0, w2 = 0, w3 = 0;
      if (e >= a0 && e < a0 + 8) {
        unsigned int bits = 0x3F80u << ((e & 1) * 16);
        if ((e - a0) >> 1 == 0) w0 = bits;
        else if ((e - a0) >> 1 == 1) w1 = bits;
        else if ((e - a0) >> 1 == 2) w2 = bits;
        else w3 = bits;
      }
      uint4 v = {w0, w1, w2, w3};
      *(uint4*)&BfT[(size_t)i8 * 8] = v;
    }
    return;
  }
  if (b < 122) {  // BfT transpose for experts 1..7
    __shared__ float tile[64][65];
    int t = b - 66;
    int k = (t >> 3);
    int e0 = (t & 7) * 64;
    const float* src = Brest + (size_t)k * ACTD * ENCD + e0;
#pragma unroll
    for (int j = 0; j < 16; j++) {
      int idx = j * 256 + tid;
      int a = idx >> 6, e = idx & 63;
      tile[a][e] = src[(size_t)a * ENCD + e];
    }
    __syncthreads();
    unsigned short* dst = BfT + ((size_t)(k + 1) * ENCD + e0) * ACTD;
#pragma unroll
    for (int j = 0; j < 16; j++) {
      int idx = j * 256 + tid;
      int e = idx >> 6, a = idx & 63;
      dst[(size_t)e * ACTD + a] = f2bf(tile[a][e]);
    }
    return;
  }
  // converts: U (1024 blocks) then A (2048 blocks)
  int cb = b - 122;
  const float* src;
  unsigned short* dst;
  size_t i;
  if (cb < 1024) { src = U; dst = Ubf; i = (size_t)cb * 256 + tid; }
  else           { src = Aall; dst = Abf; i = (size_t)(cb - 1024) * 256 + tid; }
  float4 v = ((const float4*)src)[i];
  uint2 r = {cvtpk(v.x, v.y), cvtpk(v.z, v.w)};
  *(uint2*)&dst[i * 4] = r;
}

// ---------------- routing: one THREAD per row, GT via scalar loads ---------
__global__ __launch_bounds__(128) void routing_k(
    const float* __restrict__ X0, const float* __restrict__ GT,
    const float* __restrict__ Cb, int* __restrict__ inds,
    int* __restrict__ counts) {
  __shared__ int lhist[KEXP];
  const int tid = threadIdx.x;
  if (tid < KEXP) lhist[tid] = 0;
  __syncthreads();
  const int n = blockIdx.x * 128 + tid;
  const float4* xr = (const float4*)(X0 + (size_t)n * OBSD);
  float acc[KEXP] = {};
  for (int h4 = 0; h4 < OBSD / 4; h4++) {
    float4 x = xr[h4];
    float xv[4] = {x.x, x.y, x.z, x.w};
#pragma unroll
    for (int j = 0; j < 4; j++) {
      const float* g = GT + (h4 * 4 + j) * KEXP;  // wave-uniform -> s_load
#pragma unroll
      for (int e = 0; e < KEXP; e++) acc[e] += xv[j] * g[e];
    }
  }
  int best = 0;
  float bv = acc[0] + Cb[0];
#pragma unroll
  for (int e = 1; e < KEXP; e++) {
    float v = acc[e] + Cb[e];
    if (v > bv) { bv = v; best = e; }  // strict >: first max wins (jnp.argmax)
  }
  inds[n] = best;
  atomicAdd(&lhist[best], 1);
  __syncthreads();
  if (tid < KEXP) atomicAdd(&counts[tid], lhist[tid]);
}

__global__ void prefix_k(const int* __restrict__ counts, int* __restrict__ cursor,
                         int* __restrict__ starts) {
  if (threadIdx.x == 0 && blockIdx.x == 0) {
    int s = 0;
    for (int k = 0; k < KEXP; k++) { starts[k] = s; cursor[k] = s; s += counts[k]; }
    starts[KEXP] = s;
  }
}

__global__ __launch_bounds__(256) void scatter_k(
    const int* __restrict__ inds, int* __restrict__ cursor,
    int* __restrict__ rowlist) {
  __shared__ int lhist[KEXP], lbase[KEXP];
  const int tid = threadIdx.x;
  if (tid < KEXP) lhist[tid] = 0;
  __syncthreads();
  const int n = blockIdx.x * 256 + tid;
  const int r = inds[n];
  const int lpos = atomicAdd(&lhist[r], 1);
  __syncthreads();
  if (tid < KEXP) lbase[tid] = atomicAdd(&cursor[tid], lhist[tid]);
  __syncthreads();
  rowlist[lbase[r] + lpos] = n;
}

// ---------------- encoder MFMA GEMM: E = X @ W^T (fp32 in, bf16 out) -------
// Round-4 structure (single buffer, two barriers) + register prefetch: loads
// for k0+32 are issued right after barrier 1, in flight across ds_read+MFMA
// and consumed at the next iteration's cvt (compiler-tracked vmcnt wait).
__global__ __launch_bounds__(256, 3) void enc_mfma_k(
    const float* __restrict__ X1, const float* __restrict__ X0,
    const float* __restrict__ W, unsigned short* __restrict__ X1e,
    unsigned short* __restrict__ X0e) {
  __shared__ unsigned short As[128 * 32];
  __shared__ unsigned short Bs[128 * 32];
  const int tid = threadIdx.x;
  const int bid = blockIdx.x;  // 1024 blocks, %8==0 -> bijective XCD swizzle
  const int lid = (bid & 7) * 128 + (bid >> 3);
  const int lz = lid >> 9;
  const int rem = lid & 511;
  const int col0 = (rem & 3) * 128;
  const int row0 = (rem >> 2) * 128;
  const float* X = lz ? X0 : X1;
  unsigned short* E = lz ? X0e : X1e;

  const int lane = tid & 63, w = tid >> 6;
  const int wr = w >> 1, wc = w & 1;
  const int srow = tid >> 1, sj = tid & 1;
  const int swz = (srow >> 1) & 3;
  const int wo0 = srow * 32 + ((2 * sj) ^ swz) * 8;
  const int wo1 = srow * 32 + ((2 * sj + 1) ^ swz) * 8;
  const int rslot = ((lane >> 4) ^ (((lane & 15) >> 1) & 3)) * 8;
  const int arow = wr * 64 + (lane & 15);
  const int brow = wc * 64 + (lane & 15);
  const float* pX = X + (size_t)(row0 + srow) * OBSD + sj * 16;
  const float* pW = W + (size_t)(col0 + srow) * OBSD + sj * 16;

  float4 a0, a1, a2, a3, b0, b1, b2, b3;
  auto enc_load = [&](int k0) {
    a0 = *(const float4*)(pX + k0);
    a1 = *(const float4*)(pX + k0 + 4);
    a2 = *(const float4*)(pX + k0 + 8);
    a3 = *(const float4*)(pX + k0 + 12);
    b0 = *(const float4*)(pW + k0);
    b1 = *(const float4*)(pW + k0 + 4);
    b2 = *(const float4*)(pW + k0 + 8);
    b3 = *(const float4*)(pW + k0 + 12);
  };

  enc_load(0);
  f32x4 acc[4][4] = {};
  for (int k0 = 0; k0 < OBSD; k0 += 32) {
    uint4 pa0 = {cvtpk(a0.x, a0.y), cvtpk(a0.z, a0.w), cvtpk(a1.x, a1.y), cvtpk(a1.z, a1.w)};
    uint4 pa1 = {cvtpk(a2.x, a2.y), cvtpk(a2.z, a2.w), cvtpk(a3.x, a3.y), cvtpk(a3.z, a3.w)};
    uint4 pb0 = {cvtpk(b0.x, b0.y), cvtpk(b0.z, b0.w), cvtpk(b1.x, b1.y), cvtpk(b1.z, b1.w)};
    uint4 pb1 = {cvtpk(b2.x, b2.y), cvtpk(b2.z, b2.w), cvtpk(b3.x, b3.y), cvtpk(b3.z, b3.w)};
    *(uint4*)&As[wo0] = pa0;
    *(uint4*)&As[wo1] = pa1;
    *(uint4*)&Bs[wo0] = pb0;
    *(uint4*)&Bs[wo1] = pb1;
    __syncthreads();                    // barrier 1: writes visible
    if (k0 + 32 < OBSD) enc_load(k0 + 32);  // prefetch (registers only)
    bf16x8 af[4], bfr[4];
#pragma unroll
    for (int m = 0; m < 4; m++) af[m] = *(const bf16x8*)&As[(arow + m * 16) * 32 + rslot];
#pragma unroll
    for (int n = 0; n < 4; n++) bfr[n] = *(const bf16x8*)&Bs[(brow + n * 16) * 32 + rslot];
#pragma unroll
    for (int m = 0; m < 4; m++)
#pragma unroll
      for (int n = 0; n < 4; n++)  // swapped operands: lane packs 4 consecutive cols
        acc[m][n] = __builtin_amdgcn_mfma_f32_16x16x32_bf16(bfr[n], af[m], acc[m][n], 0, 0, 0);
    __syncthreads();                    // barrier 2: reads done before next write
  }
#pragma unroll
  for (int m = 0; m < 4; m++) {
    int rowg = row0 + wr * 64 + m * 16 + (lane & 15);
#pragma unroll
    for (int n = 0; n < 4; n++) {
      int colg = col0 + wc * 64 + n * 16 + (lane >> 4) * 4;
      uint2 v = {cvtpk(acc[m][n][0], acc[m][n][1]), cvtpk(acc[m][n][2], acc[m][n][3])};
      *(uint2*)&E[(size_t)rowg * ENCD + colg] = v;
    }
  }
}

// ---------------- grouped MFMA GEMM + fused (X1e - pred)^2 -----------------
// Round-4 structure verbatim (stage -> sync -> read+MFMA -> sync).
__global__ __launch_bounds__(256, 2) void grouped_mfma_k(
    const unsigned short* __restrict__ X0ebf, const unsigned short* __restrict__ X1ebf,
    const unsigned short* __restrict__ Ubf, const unsigned short* __restrict__ Abf,
    const unsigned short* __restrict__ BfTbf, const int* __restrict__ rowlist,
    const int* __restrict__ starts, float* __restrict__ loss) {
  const int tid = threadIdx.x;
  const int bid = blockIdx.x;  // 4096 blocks
  const int lid = (bid & 7) * 512 + (bid >> 3);
  const int k = lid >> 9;
  const int rem = lid & 511;
  const int col0 = (rem & 3) * 128;
  const int tile = rem >> 2;

  const int start = starts[k];
  const int cnt = starts[k + 1] - start;
  if (tile * 128 >= cnt) return;

  __shared__ unsigned short As[128 * 32];
  __shared__ unsigned short Bs[128 * 32];
  __shared__ int ridx[128];
  __shared__ float red[4];

  if (tid < 128) {
    int p = tile * 128 + tid;
    ridx[tid] = rowlist[start + (p < cnt ? p : 0)];
  }
  __syncthreads();

  const int lane = tid & 63, w = tid >> 6;
  const int wr = w >> 1, wc = w & 1;
  const int gslot = ((tid & 3) ^ ((tid >> 3) & 3)) * 8;
  const int srow = tid >> 2;
  const int ldsoff = tid * 8;
  const int rslot = ((lane >> 4) ^ (((lane & 15) >> 1) & 3)) * 8;
  const int arow = wr * 64 + (lane & 15);
  const int brow = wc * 64 + (lane & 15);
  const int rn0 = ridx[srow];
  const int rn1 = ridx[64 + srow];

  f32x4 acc[4][4] = {};
  const unsigned short* Ak = Abf + (size_t)k * ENCD * ENCD;
  for (int k0 = 0; k0 < ENCD; k0 += 32) {
    gload_lds16(X0ebf + (size_t)rn0 * ENCD + k0 + gslot, &As[ldsoff]);
    gload_lds16(X0ebf + (size_t)rn1 * ENCD + k0 + gslot, &As[2048 + ldsoff]);
    gload_lds16(Ak + (size_t)(col0 + srow) * ENCD + k0 + gslot, &Bs[ldsoff]);
    gload_lds16(Ak + (size_t)(col0 + 64 + srow) * ENCD + k0 + gslot, &Bs[2048 + ldsoff]);
    __syncthreads();
    bf16x8 af[4], bfr[4];
#pragma unroll
    for (int m = 0; m < 4; m++) af[m] = *(const bf16x8*)&As[(arow + m * 16) * 32 + rslot];
#pragma unroll
    for (int n = 0; n < 4; n++) bfr[n] = *(const bf16x8*)&Bs[(brow + n * 16) * 32 + rslot];
#pragma unroll
    for (int m = 0; m < 4; m++)
#pragma unroll
      for (int n = 0; n < 4; n++)
        acc[m][n] = __builtin_amdgcn_mfma_f32_16x16x32_bf16(bfr[n], af[m], acc[m][n], 0, 0, 0);
    __syncthreads();
  }
  const unsigned short* BfTk = BfTbf + (size_t)k * ENCD * ACTD;
  for (int a0 = 0; a0 < ACTD; a0 += 32) {
    gload_lds16(Ubf + (size_t)rn0 * ACTD + a0 + gslot, &As[ldsoff]);
    gload_lds16(Ubf + (size_t)rn1 * ACTD + a0 + gslot, &As[2048 + ldsoff]);
    gload_lds16(BfTk + (size_t)(col0 + srow) * ACTD + a0 + gslot, &Bs[ldsoff]);
    gload_lds16(BfTk + (size_t)(col0 + 64 + srow) * ACTD + a0 + gslot, &Bs[2048 + ldsoff]);
    __syncthreads();
    bf16x8 af[4], bfr[4];
#pragma unroll
    for (int m = 0; m < 4; m++) af[m] = *(const bf16x8*)&As[(arow + m * 16) * 32 + rslot];
#pragma unroll
    for (int n = 0; n < 4; n++) bfr[n] = *(const bf16x8*)&Bs[(brow + n * 16) * 32 + rslot];
#pragma unroll
    for (int m = 0; m < 4; m++)
#pragma unroll
      for (int n = 0; n < 4; n++)
        acc[m][n] = __builtin_amdgcn_mfma_f32_16x16x32_bf16(bfr[n], af[m], acc[m][n], 0, 0, 0);
    __syncthreads();
  }
  // fused epilogue: lane owns row, 4 consecutive cols per (m,n)
  float sq = 0.f;
#pragma unroll
  for (int m = 0; m < 4; m++) {
    int lr = wr * 64 + m * 16 + (lane & 15);
    bool valid = (tile * 128 + lr) < cnt;
    const unsigned short* xrow = X1ebf + (size_t)ridx[lr] * ENCD;
#pragma unroll
    for (int n = 0; n < 4; n++) {
      int cg = col0 + wc * 64 + n * 16 + (lane >> 4) * 4;
      if (valid) {
        ushort4 x4 = *(const ushort4*)&xrow[cg];
        float d0 = bf2f(x4.x) - acc[m][n][0];
        float d1 = bf2f(x4.y) - acc[m][n][1];
        float d2 = bf2f(x4.z) - acc[m][n][2];
        float d3 = bf2f(x4.w) - acc[m][n][3];
        sq += d0 * d0 + d1 * d1 + d2 * d2 + d3 * d3;
      }
    }
  }
#pragma unroll
  for (int off = 32; off > 0; off >>= 1) sq += __shfl_xor(sq, off, 64);
  if (lane == 0) red[w] = sq;
  __syncthreads();
  if (tid == 0) atomicAdd(loss, red[0] + red[1] + red[2] + red[3]);
}

__global__ void finalize_k(const float* __restrict__ loss, float* __restrict__ out) {
  if (threadIdx.x == 0 && blockIdx.x == 0)
    out[0] = loss[0] * (1.0f / ((float)ENCD * (float)NROWS));
}

extern "C" void kernel_launch(void* const* d_in, const int* in_sizes, int n_in,
                              void* d_out, int out_size, void* d_ws, size_t ws_size,
                              hipStream_t stream) {
  const float* X1 = (const float*)d_in[0];
  const float* X0 = (const float*)d_in[1];
  const float* U = (const float*)d_in[2];
  const float* W = (const float*)d_in[3];
  const float* Aall = (const float*)d_in[4];
  const float* Brest = (const float*)d_in[5];
  const float* Cw = (const float*)d_in[6];
  const float* Cb = (const float*)d_in[7];
  float* out = (float*)d_out;

  char* p = (char*)d_ws;
  auto alloc = [&](size_t bytes) { char* r = p; p += (bytes + 255) & ~(size_t)255; return r; };
  unsigned short* Ubf = (unsigned short*)alloc((size_t)NROWS * ACTD * 2);
  unsigned short* Abf = (unsigned short*)alloc((size_t)KEXP * ENCD * ENCD * 2);
  unsigned short* BfT = (unsigned short*)alloc((size_t)KEXP * ENCD * ACTD * 2);
  unsigned short* X1ebf = (unsigned short*)alloc((size_t)NROWS * ENCD * 2);
  unsigned short* X0ebf = (unsigned short*)alloc((size_t)NROWS * ENCD * 2);
  float* GT = (float*)alloc(KEXP * OBSD * 4);
  float* loss = (float*)alloc(256);
  int* inds = (int*)alloc(NROWS * 4);
  int* rowlist = (int*)alloc(NROWS * 4);
  int* counts = (int*)alloc(64);
  int* cursor = (int*)alloc(64);
  int* starts = (int*)alloc(64);

  prep2_k<<<3194, 256, 0, stream>>>(U, W, Aall, Brest, Cw, Ubf, Abf, BfT, GT,
                                    loss, counts, cursor);
  routing_k<<<NROWS / 128, 128, 0, stream>>>(X0, GT, Cb, inds, counts);
  prefix_k<<<1, 1, 0, stream>>>(counts, cursor, starts);
  scatter_k<<<NROWS / 256, 256, 0, stream>>>(inds, cursor, rowlist);

  enc_mfma_k<<<1024, 256, 0, stream>>>(X1, X0, W, X1ebf, X0ebf);
  grouped_mfma_k<<<4096, 256, 0, stream>>>(X0ebf, X1ebf, Ubf, Abf, BfT,
                                           rowlist, starts, loss);
  finalize_k<<<1, 64, 0, stream>>>(loss, out);
}